// Round 3
// baseline (393.039 us; speedup 1.0000x reference)
//
#include <hip/hip_runtime.h>

#define IN_H 256
#define IN_W 256
#define C0   3
#define C1   32
#define H1   128
#define C2   64
#define H2   64
#define NB   32
#define K_FLAT (H2*H2*C2)   // 262144
#define NHID 128

// a1 layout: [b][parity 2][y 128][ci 32][x2 64], x = 2*x2 + parity.
#define A1_IDX(b,p,y,ci,x2) ((((((size_t)(b)*2 + (p))*H1 + (y))*C1 + (ci))*64) + (x2))

// ---------------------------------------------------------------- conv1
// in [32,256,256,3] -> a1p (planar layout above), stride2 SAME, ReLU.
__global__ __launch_bounds__(256)
void conv1_k(const float* __restrict__ in, const float* __restrict__ k1,
             const float* __restrict__ b1, float* __restrict__ a1p) {
  const int tid = threadIdx.x;
  const int ox  = tid & 127;                                       // 0..127
  const int cg  = __builtin_amdgcn_readfirstlane((tid >> 7) * 16); // 0 or 16
  const int oy  = blockIdx.x;       // 0..127
  const int b   = blockIdx.y;       // 0..31

  float acc[16];
#pragma unroll
  for (int co = 0; co < 16; ++co) acc[co] = b1[cg + co];

#pragma unroll
  for (int dy = 0; dy < 3; ++dy) {
    const int iy  = 2*oy + dy;
    if (iy >= IN_H) continue;        // block-uniform for oy==127
#pragma unroll
    for (int dx = 0; dx < 3; ++dx) {
      const int ix  = 2*ox + dx;
      const bool ok = ix < IN_W;     // per-lane only for ox==127, dx==2
      const int ixc = ok ? ix : (IN_W-1);
      const float* ip = in + ((size_t)(b*IN_H + iy)*IN_W + ixc)*C0;
      const float m  = ok ? 1.f : 0.f;
      const float v0 = ip[0] * m;
      const float v1 = ip[1] * m;
      const float v2 = ip[2] * m;
      const float* wp = k1 + (size_t)((dy*3+dx)*C0)*C1 + cg;   // [ci][co]
#pragma unroll
      for (int co = 0; co < 16; ++co)
        acc[co] = fmaf(v0, wp[co],
                  fmaf(v1, wp[C1+co],
                  fmaf(v2, wp[2*C1+co], acc[co])));
    }
  }
  const int p  = ox & 1;
  const int x2 = ox >> 1;
#pragma unroll
  for (int co = 0; co < 16; ++co)
    a1p[A1_IDX(b, p, oy, cg + co, x2)] = fmaxf(acc[co], 0.f);
}

// ---------------------------------------------------------------- conv2
// a1p (planar) -> a2 [32,64,64,64] NHWC, stride2 SAME, ReLU.
// v3 (R2 counters: VALUBusy 39%, SGPR 112 -> s_load weight stream was the
// serializer: 48 wave-uniform weights per (dy,ci) via 3x s_load_dwordx16,
// only ~1 iteration of SGPR budget -> each 192-cyc FMA chunk eats a ~200-cyc
// scalar stall). Fix: block = 1 co-group x 8 oy (4 waves x oy-pair); weights
// for the block's 16 co = 18 KB staged once in LDS, read per (dy,ci) as
// broadcast ds_read_b128 (same-addr = free), pipelined on lgkmcnt against
// the 96-FMA window. Thread work (2 ox x 16 co) and FMA order unchanged.
#define CONV2_DY_LOOP(EDGE_)                                                   \
  _Pragma("unroll")                                                            \
  for (int dy = 0; dy < 3; ++dy) {                                             \
    int iy = 2*oy + dy;                                                        \
    float rm = 1.f;                                                            \
    if (EDGE_) { if (iy >= H1) { iy = H1 - 1; rm = 0.f; } }                    \
    const float* r0 = a1p + A1_IDX(b, 0, iy, 0, 0) + 2*lx;                     \
    const float* r1 = a1p + A1_IDX(b, 1, iy, 0, 0) + 2*lx;                     \
    const float* wdy = wl + dy*(C1*3*16);                                      \
    const float m2 = EDGE_ ? rm * xm : xm;                                     \
    _Pragma("unroll 2")                                                        \
    for (int ci = 0; ci < C1; ++ci) {                                          \
      const float2 Av = *(const float2*)(r0 + (size_t)ci*64);                  \
      const float  A2 = r0[(size_t)ci*64 + 2];                                 \
      const float2 Bv = *(const float2*)(r1 + (size_t)ci*64);                  \
      const float ax = EDGE_ ? Av.x*rm : Av.x;                                 \
      const float ay = EDGE_ ? Av.y*rm : Av.y;                                 \
      const float bx = EDGE_ ? Bv.x*rm : Bv.x;                                 \
      const float by = EDGE_ ? Bv.y*rm : Bv.y;                                 \
      const float a2v = A2 * m2;                                               \
      const float* w0  = wdy + ci*48;                                          \
      const float* w1r = w0 + 16;                                              \
      const float* w2r = w0 + 32;                                              \
      _Pragma("unroll")                                                        \
      for (int co = 0; co < 16; ++co) {                                        \
        acc0[co] = fmaf(ax, w0[co],                                            \
                   fmaf(bx, w1r[co],                                           \
                   fmaf(ay,  w2r[co], acc0[co])));                             \
        acc1[co] = fmaf(ay, w0[co],                                            \
                   fmaf(by, w1r[co],                                           \
                   fmaf(a2v, w2r[co], acc1[co])));                             \
      }                                                                        \
    }                                                                          \
  }

__global__ __launch_bounds__(256)
void conv2_k(const float* __restrict__ a1p, const float* __restrict__ k2,
             const float* __restrict__ b2, float* __restrict__ a2) {
  // wl[((dy*32+ci)*3+dx)*16 + coo] : this block's co-group weights, 18432 B
  __shared__ __align__(16) float wl[3*C1*3*16];
  const int tid  = threadIdx.x;
  const int cg   = blockIdx.x >> 3;            // 0..3  (co base = 16*cg)
  const int q    = blockIdx.x & 7;             // 0..7  (oy octet)
  const int b    = blockIdx.y;

  // stage weights once: src k2[((dy*3+dx)*C1+ci)*C2 + 16*cg + coo]
  for (int i = tid; i < 3*C1*3*16; i += 256) {
    const int coo = i & 15;
    const int t   = i >> 4;        // (dy*32+ci)*3+dx
    const int dx  = t % 3;
    const int u   = t / 3;         // dy*32+ci
    const int ci  = u & 31;
    const int dy  = u >> 5;
    wl[i] = k2[((size_t)((dy*3+dx)*C1 + ci))*C2 + 16*cg + coo];
  }
  __syncthreads();

  const int w    = tid >> 6;                   // wave 0..3 -> oy pair
  const int lane = tid & 63;
  const int lx   = lane & 31;                  // ox pair: ox = 2lx, 2lx+1
  const int oys  = lane >> 5;                  // 0/1
  const int oy   = q*8 + w*2 + oys;            // 0..63

  float acc0[16], acc1[16];
#pragma unroll
  for (int co = 0; co < 16; ++co) { acc0[co] = b2[16*cg + co]; acc1[co] = acc0[co]; }

  // ox1 = 2lx+1 == 63 has its dx=2 tap at x=128 (SAME pad) -> masked.
  const float xm = (lx == 31) ? 0.f : 1.f;

  if (q == 7) {                  // contains oy=63: dy=2 row invalid (per-lane)
    CONV2_DY_LOOP(1)
  } else {
    CONV2_DY_LOOP(0)
  }

  float* op = a2 + ((size_t)((b*H2 + oy)*H2) + 2*lx)*C2 + 16*cg;
#pragma unroll
  for (int g = 0; g < 4; ++g) {
    float4 o0;
    o0.x = fmaxf(acc0[4*g+0], 0.f);
    o0.y = fmaxf(acc0[4*g+1], 0.f);
    o0.z = fmaxf(acc0[4*g+2], 0.f);
    o0.w = fmaxf(acc0[4*g+3], 0.f);
    ((float4*)op)[g] = o0;
    float4 o1;
    o1.x = fmaxf(acc1[4*g+0], 0.f);
    o1.y = fmaxf(acc1[4*g+1], 0.f);
    o1.z = fmaxf(acc1[4*g+2], 0.f);
    o1.w = fmaxf(acc1[4*g+3], 0.f);
    ((float4*)(op + C2))[g] = o1;
  }
}

// ---------------------------------------------------------------- FC1 partial
// x = a2 flat [32, 262144]; w1 [262144, 128]. v2: 2048 blocks, 128-k span,
// 18.4 KB LDS -> 8 waves/SIMD grid supply (R1 fix; was occupancy-capped).
#define FC1_G   2048
#define KSPAN   (K_FLAT / FC1_G)   // 128
#define GC1     16                 // reduce1 column-groups

__global__ __launch_bounds__(256)
void fc1_partial_k(const float* __restrict__ a2, const float* __restrict__ w1,
                   float* __restrict__ partial) {
  __shared__ __align__(16) float xT[KSPAN*36];   // 18,432 B
  const int tid = threadIdx.x;
  const int q   = tid & 31;    // n-quad: n = 4q..4q+3
  const int bo  = tid >> 5;    // 0..7 : b = 4bo..4bo+3
  const int k0  = blockIdx.x * KSPAN;

  // stage x chunk transposed: xT[k][b]
  {
    const int lb  = tid >> 3;    // 0..31
    const int lkq = tid & 7;
#pragma unroll
    for (int j = 0; j < 4; ++j) {
      const int k4 = lkq*4 + j*32;
      float4 t = *(const float4*)(a2 + (size_t)lb*K_FLAT + k0 + k4);
      xT[(k4+0)*36 + lb] = t.x;
      xT[(k4+1)*36 + lb] = t.y;
      xT[(k4+2)*36 + lb] = t.z;
      xT[(k4+3)*36 + lb] = t.w;
    }
  }
  __syncthreads();

  float4 a0 = make_float4(0.f,0.f,0.f,0.f), a1v = a0, a2v = a0, a3v = a0;
#pragma unroll 8
  for (int k = 0; k < KSPAN; ++k) {
    const float4 w4 = *(const float4*)(w1 + (size_t)(k0 + k)*NHID + 4*q);
    const float4 xb = *(const float4*)&xT[k*36 + 4*bo];
    a0.x = fmaf(xb.x, w4.x, a0.x); a0.y = fmaf(xb.x, w4.y, a0.y);
    a0.z = fmaf(xb.x, w4.z, a0.z); a0.w = fmaf(xb.x, w4.w, a0.w);
    a1v.x = fmaf(xb.y, w4.x, a1v.x); a1v.y = fmaf(xb.y, w4.y, a1v.y);
    a1v.z = fmaf(xb.y, w4.z, a1v.z); a1v.w = fmaf(xb.y, w4.w, a1v.w);
    a2v.x = fmaf(xb.z, w4.x, a2v.x); a2v.y = fmaf(xb.z, w4.y, a2v.y);
    a2v.z = fmaf(xb.z, w4.z, a2v.z); a2v.w = fmaf(xb.z, w4.w, a2v.w);
    a3v.x = fmaf(xb.w, w4.x, a3v.x); a3v.y = fmaf(xb.w, w4.y, a3v.y);
    a3v.z = fmaf(xb.w, w4.z, a3v.z); a3v.w = fmaf(xb.w, w4.w, a3v.w);
  }

  float* pp = partial + (size_t)blockIdx.x*(NB*NHID) + 4*q;
  *(float4*)(pp + (4*bo+0)*NHID) = a0;
  *(float4*)(pp + (4*bo+1)*NHID) = a1v;
  *(float4*)(pp + (4*bo+2)*NHID) = a2v;
  *(float4*)(pp + (4*bo+3)*NHID) = a3v;
}

// ---------------------------------------------------------------- FC1 reduce stage 1: 2048 -> 16
__global__ __launch_bounds__(128)
void fc1_reduce1_k(const float* __restrict__ partial, float* __restrict__ partial2) {
  const int t  = blockIdx.x*128 + threadIdx.x;  // 0..4095
  const int gc = blockIdx.y;                    // 0..15
  float s = 0.f;
#pragma unroll 8
  for (int g = gc*(FC1_G/GC1); g < gc*(FC1_G/GC1) + (FC1_G/GC1); ++g)
    s += partial[(size_t)g*(NB*NHID) + t];
  partial2[(size_t)gc*(NB*NHID) + t] = s;
}

// ---------------------------------------------------------------- FC1 reduce stage 2 (+bias+ReLU)
__global__ __launch_bounds__(256)
void fc1_reduce2_k(const float* __restrict__ partial2, const float* __restrict__ d1,
                   float* __restrict__ h) {
  const int t = blockIdx.x*256 + threadIdx.x;  // 0..4095
  float s = 0.f;
#pragma unroll
  for (int gc = 0; gc < GC1; ++gc) s += partial2[(size_t)gc*(NB*NHID) + t];
  h[t] = fmaxf(s + d1[t & (NHID-1)], 0.f);
}

// ---------------------------------------------------------------- theta = h @ w2 + d2
__global__ __launch_bounds__(192)
void theta_k(const float* __restrict__ h, const float* __restrict__ w2,
             const float* __restrict__ d2, float* __restrict__ theta) {
  const int t = threadIdx.x;
  if (t >= NB*6) return;
  const int b = t / 6, j = t % 6;
  float s0 = 0.f, s1 = 0.f, s2 = 0.f, s3 = 0.f;
  for (int n = 0; n < NHID; n += 4) {
    s0 = fmaf(h[b*NHID + n+0], w2[(n+0)*6 + j], s0);
    s1 = fmaf(h[b*NHID + n+1], w2[(n+1)*6 + j], s1);
    s2 = fmaf(h[b*NHID + n+2], w2[(n+2)*6 + j], s2);
    s3 = fmaf(h[b*NHID + n+3], w2[(n+3)*6 + j], s3);
  }
  theta[t] = (s0 + s1) + (s2 + s3) + d2[j];
}

// ---------------------------------------------------------------- grid sample (bilinear, zero pad)
__global__ __launch_bounds__(256)
void sample_k(const float* __restrict__ img, const float* __restrict__ theta,
              float* __restrict__ out) {
  const int x = threadIdx.x;
  const int y = blockIdx.x & (IN_H-1);
  const int b = blockIdx.x >> 8;
  const float* tp = theta + b*6;
  const float t0 = tp[0], t1 = tp[1], t2 = tp[2];
  const float t3 = tp[3], t4 = tp[4], t5 = tp[5];

  const float xs = (2.f*x + 1.f)*(1.f/IN_W) - 1.f;
  const float ys = (2.f*y + 1.f)*(1.f/IN_H) - 1.f;
  const float gx = fmaf(t0, xs, fmaf(t1, ys, t2));
  const float gy = fmaf(t3, xs, fmaf(t4, ys, t5));
  const float px = fmaf(gx + 1.f, 0.5f*IN_W, -0.5f);
  const float py = fmaf(gy + 1.f, 0.5f*IN_H, -0.5f);

  const float x0f = floorf(px), y0f = floorf(py);
  const int ix0 = (int)x0f, iy0 = (int)y0f;
  const float wx1 = px - x0f, wx0 = 1.f - wx1;
  const float wy1 = py - y0f, wy0 = 1.f - wy1;

  float r = 0.f, g = 0.f, bl = 0.f;
  const float* ib = img + (size_t)b*IN_H*IN_W*C0;

  auto tap = [&](int yi, int xi, float w) {
    const bool v = (xi >= 0) && (xi < IN_W) && (yi >= 0) && (yi < IN_H);
    const int xc = xi < 0 ? 0 : (xi > IN_W-1 ? IN_W-1 : xi);
    const int yc = yi < 0 ? 0 : (yi > IN_H-1 ? IN_H-1 : yi);
    const float* p = ib + ((size_t)yc*IN_W + xc)*C0;
    if (v) {
      r  = fmaf(w, p[0], r);
      g  = fmaf(w, p[1], g);
      bl = fmaf(w, p[2], bl);
    }
  };
  tap(iy0,   ix0,   wy0*wx0);
  tap(iy0,   ix0+1, wy0*wx1);
  tap(iy0+1, ix0,   wy1*wx0);
  tap(iy0+1, ix0+1, wy1*wx1);

  float* op = out + ((size_t)(b*IN_H + y)*IN_W + x)*C0;
  op[0] = r; op[1] = g; op[2] = bl;
}

// ---------------------------------------------------------------- launch
extern "C" void kernel_launch(void* const* d_in, const int* in_sizes, int n_in,
                              void* d_out, int out_size, void* d_ws, size_t ws_size,
                              hipStream_t stream) {
  const float* in = (const float*)d_in[0];
  const float* k1 = (const float*)d_in[1];
  const float* b1 = (const float*)d_in[2];
  const float* k2 = (const float*)d_in[3];
  const float* b2 = (const float*)d_in[4];
  const float* w1 = (const float*)d_in[5];
  const float* d1 = (const float*)d_in[6];
  const float* w2 = (const float*)d_in[7];
  const float* d2 = (const float*)d_in[8];
  float* out = (float*)d_out;
  float* ws  = (float*)d_ws;

  // ws layout (float offsets):
  //   a1p      [16,777,216] @ 0               (planar, exactly 64 MB)
  //   a2       [ 8,388,608] @ 16,777,216      (NHWC, matches flatten order)
  //   -- after conv2, a1p region is dead and reused: --
  //   partial  [2048*4096 = 8,388,608] @ 0
  //   partial2 [16*4096   =    65,536] @ 8,388,608
  //   h        [4096]                  @ 8,454,144
  //   theta    [192]                   @ 8,458,240
  float* a1p     = ws;
  float* a2      = ws + (size_t)16777216;
  float* partial = ws;
  float* part2   = ws + (size_t)8388608;
  float* h       = ws + (size_t)8454144;
  float* th      = ws + (size_t)8458240;

  hipLaunchKernelGGL(conv1_k,       dim3(128, 32), dim3(256), 0, stream, in, k1, b1, a1p);
  hipLaunchKernelGGL(conv2_k,       dim3(32, 32),  dim3(256), 0, stream, a1p, k2, b2, a2);
  hipLaunchKernelGGL(fc1_partial_k, dim3(FC1_G),   dim3(256), 0, stream, a2, w1, partial);
  hipLaunchKernelGGL(fc1_reduce1_k, dim3(32, GC1), dim3(128), 0, stream, partial, part2);
  hipLaunchKernelGGL(fc1_reduce2_k, dim3(16),      dim3(256), 0, stream, part2, d1, h);
  hipLaunchKernelGGL(theta_k,       dim3(1),       dim3(192), 0, stream, h, w2, d2, th);
  hipLaunchKernelGGL(sample_k,      dim3(NB*IN_H), dim3(256), 0, stream, in, th, out);
}

// Round 4
// 362.132 us; speedup vs baseline: 1.0853x; 1.0853x over previous
//
#include <hip/hip_runtime.h>

#define IN_H 256
#define IN_W 256
#define C0   3
#define C1   32
#define H1   128
#define C2   64
#define H2   64
#define NB   32
#define K_FLAT (H2*H2*C2)   // 262144
#define NHID 128

// a1 layout: [b][parity 2][y 128][ci 32][x2 64], x = 2*x2 + parity.
#define A1_IDX(b,p,y,ci,x2) ((((((size_t)(b)*2 + (p))*H1 + (y))*C1 + (ci))*64) + (x2))

// ---------------------------------------------------------------- conv1
// in [32,256,256,3] -> a1p (planar layout above), stride2 SAME, ReLU.
// VGPR 24, 16 waves/SIMD grid supply — latency well hidden, leave as is.
__global__ __launch_bounds__(256)
void conv1_k(const float* __restrict__ in, const float* __restrict__ k1,
             const float* __restrict__ b1, float* __restrict__ a1p) {
  const int tid = threadIdx.x;
  const int ox  = tid & 127;                                       // 0..127
  const int cg  = __builtin_amdgcn_readfirstlane((tid >> 7) * 16); // 0 or 16
  const int oy  = blockIdx.x;       // 0..127
  const int b   = blockIdx.y;       // 0..31

  float acc[16];
#pragma unroll
  for (int co = 0; co < 16; ++co) acc[co] = b1[cg + co];

#pragma unroll
  for (int dy = 0; dy < 3; ++dy) {
    const int iy  = 2*oy + dy;
    if (iy >= IN_H) continue;        // block-uniform for oy==127
#pragma unroll
    for (int dx = 0; dx < 3; ++dx) {
      const int ix  = 2*ox + dx;
      const bool ok = ix < IN_W;     // per-lane only for ox==127, dx==2
      const int ixc = ok ? ix : (IN_W-1);
      const float* ip = in + ((size_t)(b*IN_H + iy)*IN_W + ixc)*C0;
      const float m  = ok ? 1.f : 0.f;
      const float v0 = ip[0] * m;
      const float v1 = ip[1] * m;
      const float v2 = ip[2] * m;
      const float* wp = k1 + (size_t)((dy*3+dx)*C0)*C1 + cg;   // [ci][co]
#pragma unroll
      for (int co = 0; co < 16; ++co)
        acc[co] = fmaf(v0, wp[co],
                  fmaf(v1, wp[C1+co],
                  fmaf(v2, wp[2*C1+co], acc[co])));
    }
  }
  const int p  = ox & 1;
  const int x2 = ox >> 1;
#pragma unroll
  for (int co = 0; co < 16; ++co)
    a1p[A1_IDX(b, p, oy, cg + co, x2)] = fmaxf(acc[co], 0.f);
}

// ---------------------------------------------------------------- conv2
// a1p (planar) -> a2 [32,64,64,64] NHWC, stride2 SAME, ReLU.
// v4 = v2 structure (R3's LDS-weights experiment REGRESSED 82->108, reverted)
// + __launch_bounds__(256,4) + unroll 8.
// R3 post-mortem: v2's VGPR_Count=32 (accs only!) meant the compiler had NO
// registers for in-flight loads -> MLP depth ~1, each of the ~6 mem ops/iter
// ate a full ~340cyc latency serially (measured: 2060 cyc/iter wall vs 200
// exec). Grid is 4 blocks/CU (hard cap 4 waves/SIMD), so capping occupancy
// at 4 waves/EU (128 VGPR) is FREE and buys ~90 regs of load pipelining.
#define CONV2_DY_LOOP(EDGE_)                                                   \
  _Pragma("unroll")                                                            \
  for (int dy = 0; dy < 3; ++dy) {                                             \
    int iy = 2*oy + dy;                                                        \
    float rm = 1.f;                                                            \
    if (EDGE_) { if (iy >= H1) { iy = H1 - 1; rm = 0.f; } }                    \
    const float* r0 = a1p + A1_IDX(b, 0, iy, 0, 0) + 2*lx;                     \
    const float* r1 = a1p + A1_IDX(b, 1, iy, 0, 0) + 2*lx;                     \
    const float* wp = k2 + (size_t)(dy*3*C1)*C2 + cg16;                        \
    const float m2 = EDGE_ ? rm * xm : xm;                                     \
    _Pragma("unroll 8")                                                        \
    for (int ci = 0; ci < C1; ++ci) {                                          \
      const float2 Av = *(const float2*)(r0 + (size_t)ci*64);                  \
      const float  A2 = r0[(size_t)ci*64 + 2];                                 \
      const float2 Bv = *(const float2*)(r1 + (size_t)ci*64);                  \
      const float ax = EDGE_ ? Av.x*rm : Av.x;                                 \
      const float ay = EDGE_ ? Av.y*rm : Av.y;                                 \
      const float bx = EDGE_ ? Bv.x*rm : Bv.x;                                 \
      const float by = EDGE_ ? Bv.y*rm : Bv.y;                                 \
      const float a2v = A2 * m2;                                               \
      const float* w0  = wp + (size_t)ci*C2;                                   \
      const float* w1r = wp + (size_t)(C1 + ci)*C2;                            \
      const float* w2r = wp + (size_t)(2*C1 + ci)*C2;                          \
      _Pragma("unroll")                                                        \
      for (int co = 0; co < 16; ++co) {                                        \
        acc0[co] = fmaf(ax, w0[co],                                            \
                   fmaf(bx, w1r[co],                                           \
                   fmaf(ay,  w2r[co], acc0[co])));                             \
        acc1[co] = fmaf(ay, w0[co],                                            \
                   fmaf(by, w1r[co],                                           \
                   fmaf(a2v, w2r[co], acc1[co])));                             \
      }                                                                        \
    }                                                                          \
  }

__global__ __launch_bounds__(256, 4)
void conv2_k(const float* __restrict__ a1p, const float* __restrict__ k2,
             const float* __restrict__ b2, float* __restrict__ a2) {
  const int tid  = threadIdx.x;
  const int lane = tid & 63;
  const int lx   = lane & 31;                                       // ox pair
  const int oys  = lane >> 5;                                       // 0/1
  const int cg16 = __builtin_amdgcn_readfirstlane((tid >> 6) * 16); // co base
  const int oy   = blockIdx.x * 2 + oys;                            // 0..63
  const int b    = blockIdx.y;

  float acc0[16], acc1[16];
#pragma unroll
  for (int co = 0; co < 16; ++co) { acc0[co] = b2[cg16 + co]; acc1[co] = acc0[co]; }

  // ox1 = 2lx+1 == 63 has its dx=2 tap at x=128 (SAME pad) -> masked.
  const float xm = (lx == 31) ? 0.f : 1.f;

  if (blockIdx.x == 31) {            // contains oy=63: dy=2 row invalid (per-lane)
    CONV2_DY_LOOP(1)
  } else {
    CONV2_DY_LOOP(0)
  }

  float* op = a2 + ((size_t)((b*H2 + oy)*H2) + 2*lx)*C2 + cg16;
#pragma unroll
  for (int g = 0; g < 4; ++g) {
    float4 o0;
    o0.x = fmaxf(acc0[4*g+0], 0.f);
    o0.y = fmaxf(acc0[4*g+1], 0.f);
    o0.z = fmaxf(acc0[4*g+2], 0.f);
    o0.w = fmaxf(acc0[4*g+3], 0.f);
    ((float4*)op)[g] = o0;
    float4 o1;
    o1.x = fmaxf(acc1[4*g+0], 0.f);
    o1.y = fmaxf(acc1[4*g+1], 0.f);
    o1.z = fmaxf(acc1[4*g+2], 0.f);
    o1.w = fmaxf(acc1[4*g+3], 0.f);
    ((float4*)(op + C2))[g] = o1;
  }
}

// ---------------------------------------------------------------- FC1 partial
// x = a2 flat [32, 262144]; w1 [262144, 128]. v2: 2048 blocks, 128-k span,
// 18.4 KB LDS -> 8 waves/SIMD grid supply (R1 fix).
#define FC1_G   2048
#define KSPAN   (K_FLAT / FC1_G)   // 128
#define GC1     16                 // reduce1 column-groups

__global__ __launch_bounds__(256)
void fc1_partial_k(const float* __restrict__ a2, const float* __restrict__ w1,
                   float* __restrict__ partial) {
  __shared__ __align__(16) float xT[KSPAN*36];   // 18,432 B
  const int tid = threadIdx.x;
  const int q   = tid & 31;    // n-quad: n = 4q..4q+3
  const int bo  = tid >> 5;    // 0..7 : b = 4bo..4bo+3
  const int k0  = blockIdx.x * KSPAN;

  // stage x chunk transposed: xT[k][b]
  {
    const int lb  = tid >> 3;    // 0..31
    const int lkq = tid & 7;
#pragma unroll
    for (int j = 0; j < 4; ++j) {
      const int k4 = lkq*4 + j*32;
      float4 t = *(const float4*)(a2 + (size_t)lb*K_FLAT + k0 + k4);
      xT[(k4+0)*36 + lb] = t.x;
      xT[(k4+1)*36 + lb] = t.y;
      xT[(k4+2)*36 + lb] = t.z;
      xT[(k4+3)*36 + lb] = t.w;
    }
  }
  __syncthreads();

  float4 a0 = make_float4(0.f,0.f,0.f,0.f), a1v = a0, a2v = a0, a3v = a0;
#pragma unroll 8
  for (int k = 0; k < KSPAN; ++k) {
    const float4 w4 = *(const float4*)(w1 + (size_t)(k0 + k)*NHID + 4*q);
    const float4 xb = *(const float4*)&xT[k*36 + 4*bo];
    a0.x = fmaf(xb.x, w4.x, a0.x); a0.y = fmaf(xb.x, w4.y, a0.y);
    a0.z = fmaf(xb.x, w4.z, a0.z); a0.w = fmaf(xb.x, w4.w, a0.w);
    a1v.x = fmaf(xb.y, w4.x, a1v.x); a1v.y = fmaf(xb.y, w4.y, a1v.y);
    a1v.z = fmaf(xb.y, w4.z, a1v.z); a1v.w = fmaf(xb.y, w4.w, a1v.w);
    a2v.x = fmaf(xb.z, w4.x, a2v.x); a2v.y = fmaf(xb.z, w4.y, a2v.y);
    a2v.z = fmaf(xb.z, w4.z, a2v.z); a2v.w = fmaf(xb.z, w4.w, a2v.w);
    a3v.x = fmaf(xb.w, w4.x, a3v.x); a3v.y = fmaf(xb.w, w4.y, a3v.y);
    a3v.z = fmaf(xb.w, w4.z, a3v.z); a3v.w = fmaf(xb.w, w4.w, a3v.w);
  }

  float* pp = partial + (size_t)blockIdx.x*(NB*NHID) + 4*q;
  *(float4*)(pp + (4*bo+0)*NHID) = a0;
  *(float4*)(pp + (4*bo+1)*NHID) = a1v;
  *(float4*)(pp + (4*bo+2)*NHID) = a2v;
  *(float4*)(pp + (4*bo+3)*NHID) = a3v;
}

// ---------------------------------------------------------------- FC1 reduce stage 1: 2048 -> 16
__global__ __launch_bounds__(128)
void fc1_reduce1_k(const float* __restrict__ partial, float* __restrict__ partial2) {
  const int t  = blockIdx.x*128 + threadIdx.x;  // 0..4095
  const int gc = blockIdx.y;                    // 0..15
  float s = 0.f;
#pragma unroll 8
  for (int g = gc*(FC1_G/GC1); g < gc*(FC1_G/GC1) + (FC1_G/GC1); ++g)
    s += partial[(size_t)g*(NB*NHID) + t];
  partial2[(size_t)gc*(NB*NHID) + t] = s;
}

// ---------------------------------------------------------------- FC1 reduce stage 2 (+bias+ReLU)
__global__ __launch_bounds__(256)
void fc1_reduce2_k(const float* __restrict__ partial2, const float* __restrict__ d1,
                   float* __restrict__ h) {
  const int t = blockIdx.x*256 + threadIdx.x;  // 0..4095
  float s = 0.f;
#pragma unroll
  for (int gc = 0; gc < GC1; ++gc) s += partial2[(size_t)gc*(NB*NHID) + t];
  h[t] = fmaxf(s + d1[t & (NHID-1)], 0.f);
}

// ---------------------------------------------------------------- theta = h @ w2 + d2
__global__ __launch_bounds__(192)
void theta_k(const float* __restrict__ h, const float* __restrict__ w2,
             const float* __restrict__ d2, float* __restrict__ theta) {
  const int t = threadIdx.x;
  if (t >= NB*6) return;
  const int b = t / 6, j = t % 6;
  float s0 = 0.f, s1 = 0.f, s2 = 0.f, s3 = 0.f;
  for (int n = 0; n < NHID; n += 4) {
    s0 = fmaf(h[b*NHID + n+0], w2[(n+0)*6 + j], s0);
    s1 = fmaf(h[b*NHID + n+1], w2[(n+1)*6 + j], s1);
    s2 = fmaf(h[b*NHID + n+2], w2[(n+2)*6 + j], s2);
    s3 = fmaf(h[b*NHID + n+3], w2[(n+3)*6 + j], s3);
  }
  theta[t] = (s0 + s1) + (s2 + s3) + d2[j];
}

// ---------------------------------------------------------------- grid sample (bilinear, zero pad)
__global__ __launch_bounds__(256)
void sample_k(const float* __restrict__ img, const float* __restrict__ theta,
              float* __restrict__ out) {
  const int x = threadIdx.x;
  const int y = blockIdx.x & (IN_H-1);
  const int b = blockIdx.x >> 8;
  const float* tp = theta + b*6;
  const float t0 = tp[0], t1 = tp[1], t2 = tp[2];
  const float t3 = tp[3], t4 = tp[4], t5 = tp[5];

  const float xs = (2.f*x + 1.f)*(1.f/IN_W) - 1.f;
  const float ys = (2.f*y + 1.f)*(1.f/IN_H) - 1.f;
  const float gx = fmaf(t0, xs, fmaf(t1, ys, t2));
  const float gy = fmaf(t3, xs, fmaf(t4, ys, t5));
  const float px = fmaf(gx + 1.f, 0.5f*IN_W, -0.5f);
  const float py = fmaf(gy + 1.f, 0.5f*IN_H, -0.5f);

  const float x0f = floorf(px), y0f = floorf(py);
  const int ix0 = (int)x0f, iy0 = (int)y0f;
  const float wx1 = px - x0f, wx0 = 1.f - wx1;
  const float wy1 = py - y0f, wy0 = 1.f - wy1;

  float r = 0.f, g = 0.f, bl = 0.f;
  const float* ib = img + (size_t)b*IN_H*IN_W*C0;

  auto tap = [&](int yi, int xi, float w) {
    const bool v = (xi >= 0) && (xi < IN_W) && (yi >= 0) && (yi < IN_H);
    const int xc = xi < 0 ? 0 : (xi > IN_W-1 ? IN_W-1 : xi);
    const int yc = yi < 0 ? 0 : (yi > IN_H-1 ? IN_H-1 : yi);
    const float* p = ib + ((size_t)yc*IN_W + xc)*C0;
    if (v) {
      r  = fmaf(w, p[0], r);
      g  = fmaf(w, p[1], g);
      bl = fmaf(w, p[2], bl);
    }
  };
  tap(iy0,   ix0,   wy0*wx0);
  tap(iy0,   ix0+1, wy0*wx1);
  tap(iy0+1, ix0,   wy1*wx0);
  tap(iy0+1, ix0+1, wy1*wx1);

  float* op = out + ((size_t)(b*IN_H + y)*IN_W + x)*C0;
  op[0] = r; op[1] = g; op[2] = bl;
}

// ---------------------------------------------------------------- launch
extern "C" void kernel_launch(void* const* d_in, const int* in_sizes, int n_in,
                              void* d_out, int out_size, void* d_ws, size_t ws_size,
                              hipStream_t stream) {
  const float* in = (const float*)d_in[0];
  const float* k1 = (const float*)d_in[1];
  const float* b1 = (const float*)d_in[2];
  const float* k2 = (const float*)d_in[3];
  const float* b2 = (const float*)d_in[4];
  const float* w1 = (const float*)d_in[5];
  const float* d1 = (const float*)d_in[6];
  const float* w2 = (const float*)d_in[7];
  const float* d2 = (const float*)d_in[8];
  float* out = (float*)d_out;
  float* ws  = (float*)d_ws;

  // ws layout (float offsets):
  //   a1p      [16,777,216] @ 0               (planar, exactly 64 MB)
  //   a2       [ 8,388,608] @ 16,777,216      (NHWC, matches flatten order)
  //   -- after conv2, a1p region is dead and reused: --
  //   partial  [2048*4096 = 8,388,608] @ 0
  //   partial2 [16*4096   =    65,536] @ 8,388,608
  //   h        [4096]                  @ 8,454,144
  //   theta    [192]                   @ 8,458,240
  float* a1p     = ws;
  float* a2      = ws + (size_t)16777216;
  float* partial = ws;
  float* part2   = ws + (size_t)8388608;
  float* h       = ws + (size_t)8454144;
  float* th      = ws + (size_t)8458240;

  hipLaunchKernelGGL(conv1_k,       dim3(128, 32), dim3(256), 0, stream, in, k1, b1, a1p);
  hipLaunchKernelGGL(conv2_k,       dim3(32, 32),  dim3(256), 0, stream, a1p, k2, b2, a2);
  hipLaunchKernelGGL(fc1_partial_k, dim3(FC1_G),   dim3(256), 0, stream, a2, w1, partial);
  hipLaunchKernelGGL(fc1_reduce1_k, dim3(32, GC1), dim3(128), 0, stream, partial, part2);
  hipLaunchKernelGGL(fc1_reduce2_k, dim3(16),      dim3(256), 0, stream, part2, d1, h);
  hipLaunchKernelGGL(theta_k,       dim3(1),       dim3(192), 0, stream, h, w2, d2, th);
  hipLaunchKernelGGL(sample_k,      dim3(NB*IN_H), dim3(256), 0, stream, in, th, out);
}

// Round 5
// 360.721 us; speedup vs baseline: 1.0896x; 1.0039x over previous
//
#include <hip/hip_runtime.h>

#define IN_H 256
#define IN_W 256
#define C0   3
#define C1   32
#define H1   128
#define C2   64
#define H2   64
#define NB   32
#define K_FLAT (H2*H2*C2)   // 262144
#define NHID 128

// a1 layout: [b][parity 2][y 128][ci 32][x2 64], x = 2*x2 + parity.
#define A1_IDX(b,p,y,ci,x2) ((((((size_t)(b)*2 + (p))*H1 + (y))*C1 + (ci))*64) + (x2))

// ---------------------------------------------------------------- conv1
// in [32,256,256,3] -> a1p (planar layout above), stride2 SAME, ReLU.
// v2: + __launch_bounds__(256,8). R4 lesson (conv2/fc1): with no waves/EU
// hint the compiler minimizes VGPRs (24 here) and leaves no registers for
// in-flight loads -> serialized latency. 8 waves/EU = 64-VGPR budget, free
// (residency is >=8 waves/SIMD anyway).
__global__ __launch_bounds__(256, 8)
void conv1_k(const float* __restrict__ in, const float* __restrict__ k1,
             const float* __restrict__ b1, float* __restrict__ a1p) {
  const int tid = threadIdx.x;
  const int ox  = tid & 127;                                       // 0..127
  const int cg  = __builtin_amdgcn_readfirstlane((tid >> 7) * 16); // 0 or 16
  const int oy  = blockIdx.x;       // 0..127
  const int b   = blockIdx.y;       // 0..31

  float acc[16];
#pragma unroll
  for (int co = 0; co < 16; ++co) acc[co] = b1[cg + co];

#pragma unroll
  for (int dy = 0; dy < 3; ++dy) {
    const int iy  = 2*oy + dy;
    if (iy >= IN_H) continue;        // block-uniform for oy==127
#pragma unroll
    for (int dx = 0; dx < 3; ++dx) {
      const int ix  = 2*ox + dx;
      const bool ok = ix < IN_W;     // per-lane only for ox==127, dx==2
      const int ixc = ok ? ix : (IN_W-1);
      const float* ip = in + ((size_t)(b*IN_H + iy)*IN_W + ixc)*C0;
      const float m  = ok ? 1.f : 0.f;
      const float v0 = ip[0] * m;
      const float v1 = ip[1] * m;
      const float v2 = ip[2] * m;
      const float* wp = k1 + (size_t)((dy*3+dx)*C0)*C1 + cg;   // [ci][co]
#pragma unroll
      for (int co = 0; co < 16; ++co)
        acc[co] = fmaf(v0, wp[co],
                  fmaf(v1, wp[C1+co],
                  fmaf(v2, wp[2*C1+co], acc[co])));
    }
  }
  const int p  = ox & 1;
  const int x2 = ox >> 1;
#pragma unroll
  for (int co = 0; co < 16; ++co)
    a1p[A1_IDX(b, p, oy, cg + co, x2)] = fmaxf(acc[co], 0.f);
}

// ---------------------------------------------------------------- conv2
// a1p (planar) -> a2 [32,64,64,64] NHWC, stride2 SAME, ReLU.
// v4 = v2 structure + __launch_bounds__(256,4) + unroll 8 (R4: worked,
// out of top-5). Grid is 4 blocks/CU (hard cap 4 waves/SIMD), so the
// 128-VGPR budget is free and buys ~90 regs of load pipelining.
#define CONV2_DY_LOOP(EDGE_)                                                   \
  _Pragma("unroll")                                                            \
  for (int dy = 0; dy < 3; ++dy) {                                             \
    int iy = 2*oy + dy;                                                        \
    float rm = 1.f;                                                            \
    if (EDGE_) { if (iy >= H1) { iy = H1 - 1; rm = 0.f; } }                    \
    const float* r0 = a1p + A1_IDX(b, 0, iy, 0, 0) + 2*lx;                     \
    const float* r1 = a1p + A1_IDX(b, 1, iy, 0, 0) + 2*lx;                     \
    const float* wp = k2 + (size_t)(dy*3*C1)*C2 + cg16;                        \
    const float m2 = EDGE_ ? rm * xm : xm;                                     \
    _Pragma("unroll 8")                                                        \
    for (int ci = 0; ci < C1; ++ci) {                                          \
      const float2 Av = *(const float2*)(r0 + (size_t)ci*64);                  \
      const float  A2 = r0[(size_t)ci*64 + 2];                                 \
      const float2 Bv = *(const float2*)(r1 + (size_t)ci*64);                  \
      const float ax = EDGE_ ? Av.x*rm : Av.x;                                 \
      const float ay = EDGE_ ? Av.y*rm : Av.y;                                 \
      const float bx = EDGE_ ? Bv.x*rm : Bv.x;                                 \
      const float by = EDGE_ ? Bv.y*rm : Bv.y;                                 \
      const float a2v = A2 * m2;                                               \
      const float* w0  = wp + (size_t)ci*C2;                                   \
      const float* w1r = wp + (size_t)(C1 + ci)*C2;                            \
      const float* w2r = wp + (size_t)(2*C1 + ci)*C2;                          \
      _Pragma("unroll")                                                        \
      for (int co = 0; co < 16; ++co) {                                        \
        acc0[co] = fmaf(ax, w0[co],                                            \
                   fmaf(bx, w1r[co],                                           \
                   fmaf(ay,  w2r[co], acc0[co])));                             \
        acc1[co] = fmaf(ay, w0[co],                                            \
                   fmaf(by, w1r[co],                                           \
                   fmaf(a2v, w2r[co], acc1[co])));                             \
      }                                                                        \
    }                                                                          \
  }

__global__ __launch_bounds__(256, 4)
void conv2_k(const float* __restrict__ a1p, const float* __restrict__ k2,
             const float* __restrict__ b2, float* __restrict__ a2) {
  const int tid  = threadIdx.x;
  const int lane = tid & 63;
  const int lx   = lane & 31;                                       // ox pair
  const int oys  = lane >> 5;                                       // 0/1
  const int cg16 = __builtin_amdgcn_readfirstlane((tid >> 6) * 16); // co base
  const int oy   = blockIdx.x * 2 + oys;                            // 0..63
  const int b    = blockIdx.y;

  float acc0[16], acc1[16];
#pragma unroll
  for (int co = 0; co < 16; ++co) { acc0[co] = b2[cg16 + co]; acc1[co] = acc0[co]; }

  // ox1 = 2lx+1 == 63 has its dx=2 tap at x=128 (SAME pad) -> masked.
  const float xm = (lx == 31) ? 0.f : 1.f;

  if (blockIdx.x == 31) {            // contains oy=63: dy=2 row invalid (per-lane)
    CONV2_DY_LOOP(1)
  } else {
    CONV2_DY_LOOP(0)
  }

  float* op = a2 + ((size_t)((b*H2 + oy)*H2) + 2*lx)*C2 + cg16;
#pragma unroll
  for (int g = 0; g < 4; ++g) {
    float4 o0;
    o0.x = fmaxf(acc0[4*g+0], 0.f);
    o0.y = fmaxf(acc0[4*g+1], 0.f);
    o0.z = fmaxf(acc0[4*g+2], 0.f);
    o0.w = fmaxf(acc0[4*g+3], 0.f);
    ((float4*)op)[g] = o0;
    float4 o1;
    o1.x = fmaxf(acc1[4*g+0], 0.f);
    o1.y = fmaxf(acc1[4*g+1], 0.f);
    o1.z = fmaxf(acc1[4*g+2], 0.f);
    o1.w = fmaxf(acc1[4*g+3], 0.f);
    ((float4*)(op + C2))[g] = o1;
  }
}

// ---------------------------------------------------------------- FC1 partial
// x = a2 flat [32, 262144]; w1 [262144, 128]. v3 (R4 counters: VGPR_Count=36
// -> same register-starved-MLP pathology as conv2: 16 accs + addresses left
// ~2 float4 load buffers, so the unroll-8 batch pipelined only ~2 deep and
// each w-load ate ~300cyc L2/L3 latency. VALUBusy 20% = pure exec/wall
// ratio at MLP~2). Fix: __launch_bounds__(256,8) -> 64-VGPR budget (free:
// LDS already caps at 8 blocks/CU = 8 waves/SIMD). 2048 blocks, 128-k span.
#define FC1_G   2048
#define KSPAN   (K_FLAT / FC1_G)   // 128
#define GC1     16                 // reduce1 column-groups

__global__ __launch_bounds__(256, 8)
void fc1_partial_k(const float* __restrict__ a2, const float* __restrict__ w1,
                   float* __restrict__ partial) {
  __shared__ __align__(16) float xT[KSPAN*36];   // 18,432 B
  const int tid = threadIdx.x;
  const int q   = tid & 31;    // n-quad: n = 4q..4q+3
  const int bo  = tid >> 5;    // 0..7 : b = 4bo..4bo+3
  const int k0  = blockIdx.x * KSPAN;

  // stage x chunk transposed: xT[k][b]
  {
    const int lb  = tid >> 3;    // 0..31
    const int lkq = tid & 7;
#pragma unroll
    for (int j = 0; j < 4; ++j) {
      const int k4 = lkq*4 + j*32;
      float4 t = *(const float4*)(a2 + (size_t)lb*K_FLAT + k0 + k4);
      xT[(k4+0)*36 + lb] = t.x;
      xT[(k4+1)*36 + lb] = t.y;
      xT[(k4+2)*36 + lb] = t.z;
      xT[(k4+3)*36 + lb] = t.w;
    }
  }
  __syncthreads();

  float4 a0 = make_float4(0.f,0.f,0.f,0.f), a1v = a0, a2v = a0, a3v = a0;
#pragma unroll 8
  for (int k = 0; k < KSPAN; ++k) {
    const float4 w4 = *(const float4*)(w1 + (size_t)(k0 + k)*NHID + 4*q);
    const float4 xb = *(const float4*)&xT[k*36 + 4*bo];
    a0.x = fmaf(xb.x, w4.x, a0.x); a0.y = fmaf(xb.x, w4.y, a0.y);
    a0.z = fmaf(xb.x, w4.z, a0.z); a0.w = fmaf(xb.x, w4.w, a0.w);
    a1v.x = fmaf(xb.y, w4.x, a1v.x); a1v.y = fmaf(xb.y, w4.y, a1v.y);
    a1v.z = fmaf(xb.y, w4.z, a1v.z); a1v.w = fmaf(xb.y, w4.w, a1v.w);
    a2v.x = fmaf(xb.z, w4.x, a2v.x); a2v.y = fmaf(xb.z, w4.y, a2v.y);
    a2v.z = fmaf(xb.z, w4.z, a2v.z); a2v.w = fmaf(xb.z, w4.w, a2v.w);
    a3v.x = fmaf(xb.w, w4.x, a3v.x); a3v.y = fmaf(xb.w, w4.y, a3v.y);
    a3v.z = fmaf(xb.w, w4.z, a3v.z); a3v.w = fmaf(xb.w, w4.w, a3v.w);
  }

  float* pp = partial + (size_t)blockIdx.x*(NB*NHID) + 4*q;
  *(float4*)(pp + (4*bo+0)*NHID) = a0;
  *(float4*)(pp + (4*bo+1)*NHID) = a1v;
  *(float4*)(pp + (4*bo+2)*NHID) = a2v;
  *(float4*)(pp + (4*bo+3)*NHID) = a3v;
}

// ---------------------------------------------------------------- FC1 reduce stage 1: 2048 -> 16
__global__ __launch_bounds__(128, 8)
void fc1_reduce1_k(const float* __restrict__ partial, float* __restrict__ partial2) {
  const int t  = blockIdx.x*128 + threadIdx.x;  // 0..4095
  const int gc = blockIdx.y;                    // 0..15
  float s = 0.f;
#pragma unroll 8
  for (int g = gc*(FC1_G/GC1); g < gc*(FC1_G/GC1) + (FC1_G/GC1); ++g)
    s += partial[(size_t)g*(NB*NHID) + t];
  partial2[(size_t)gc*(NB*NHID) + t] = s;
}

// ---------------------------------------------------------------- FC1 reduce stage 2 (+bias+ReLU)
__global__ __launch_bounds__(256)
void fc1_reduce2_k(const float* __restrict__ partial2, const float* __restrict__ d1,
                   float* __restrict__ h) {
  const int t = blockIdx.x*256 + threadIdx.x;  // 0..4095
  float s = 0.f;
#pragma unroll
  for (int gc = 0; gc < GC1; ++gc) s += partial2[(size_t)gc*(NB*NHID) + t];
  h[t] = fmaxf(s + d1[t & (NHID-1)], 0.f);
}

// ---------------------------------------------------------------- theta = h @ w2 + d2
__global__ __launch_bounds__(192)
void theta_k(const float* __restrict__ h, const float* __restrict__ w2,
             const float* __restrict__ d2, float* __restrict__ theta) {
  const int t = threadIdx.x;
  if (t >= NB*6) return;
  const int b = t / 6, j = t % 6;
  float s0 = 0.f, s1 = 0.f, s2 = 0.f, s3 = 0.f;
  for (int n = 0; n < NHID; n += 4) {
    s0 = fmaf(h[b*NHID + n+0], w2[(n+0)*6 + j], s0);
    s1 = fmaf(h[b*NHID + n+1], w2[(n+1)*6 + j], s1);
    s2 = fmaf(h[b*NHID + n+2], w2[(n+2)*6 + j], s2);
    s3 = fmaf(h[b*NHID + n+3], w2[(n+3)*6 + j], s3);
  }
  theta[t] = (s0 + s1) + (s2 + s3) + d2[j];
}

// ---------------------------------------------------------------- grid sample (bilinear, zero pad)
__global__ __launch_bounds__(256)
void sample_k(const float* __restrict__ img, const float* __restrict__ theta,
              float* __restrict__ out) {
  const int x = threadIdx.x;
  const int y = blockIdx.x & (IN_H-1);
  const int b = blockIdx.x >> 8;
  const float* tp = theta + b*6;
  const float t0 = tp[0], t1 = tp[1], t2 = tp[2];
  const float t3 = tp[3], t4 = tp[4], t5 = tp[5];

  const float xs = (2.f*x + 1.f)*(1.f/IN_W) - 1.f;
  const float ys = (2.f*y + 1.f)*(1.f/IN_H) - 1.f;
  const float gx = fmaf(t0, xs, fmaf(t1, ys, t2));
  const float gy = fmaf(t3, xs, fmaf(t4, ys, t5));
  const float px = fmaf(gx + 1.f, 0.5f*IN_W, -0.5f);
  const float py = fmaf(gy + 1.f, 0.5f*IN_H, -0.5f);

  const float x0f = floorf(px), y0f = floorf(py);
  const int ix0 = (int)x0f, iy0 = (int)y0f;
  const float wx1 = px - x0f, wx0 = 1.f - wx1;
  const float wy1 = py - y0f, wy0 = 1.f - wy1;

  float r = 0.f, g = 0.f, bl = 0.f;
  const float* ib = img + (size_t)b*IN_H*IN_W*C0;

  auto tap = [&](int yi, int xi, float w) {
    const bool v = (xi >= 0) && (xi < IN_W) && (yi >= 0) && (yi < IN_H);
    const int xc = xi < 0 ? 0 : (xi > IN_W-1 ? IN_W-1 : xi);
    const int yc = yi < 0 ? 0 : (yi > IN_H-1 ? IN_H-1 : yi);
    const float* p = ib + ((size_t)yc*IN_W + xc)*C0;
    if (v) {
      r  = fmaf(w, p[0], r);
      g  = fmaf(w, p[1], g);
      bl = fmaf(w, p[2], bl);
    }
  };
  tap(iy0,   ix0,   wy0*wx0);
  tap(iy0,   ix0+1, wy0*wx1);
  tap(iy0+1, ix0,   wy1*wx0);
  tap(iy0+1, ix0+1, wy1*wx1);

  float* op = out + ((size_t)(b*IN_H + y)*IN_W + x)*C0;
  op[0] = r; op[1] = g; op[2] = bl;
}

// ---------------------------------------------------------------- launch
extern "C" void kernel_launch(void* const* d_in, const int* in_sizes, int n_in,
                              void* d_out, int out_size, void* d_ws, size_t ws_size,
                              hipStream_t stream) {
  const float* in = (const float*)d_in[0];
  const float* k1 = (const float*)d_in[1];
  const float* b1 = (const float*)d_in[2];
  const float* k2 = (const float*)d_in[3];
  const float* b2 = (const float*)d_in[4];
  const float* w1 = (const float*)d_in[5];
  const float* d1 = (const float*)d_in[6];
  const float* w2 = (const float*)d_in[7];
  const float* d2 = (const float*)d_in[8];
  float* out = (float*)d_out;
  float* ws  = (float*)d_ws;

  // ws layout (float offsets):
  //   a1p      [16,777,216] @ 0               (planar, exactly 64 MB)
  //   a2       [ 8,388,608] @ 16,777,216      (NHWC, matches flatten order)
  //   -- after conv2, a1p region is dead and reused: --
  //   partial  [2048*4096 = 8,388,608] @ 0
  //   partial2 [16*4096   =    65,536] @ 8,388,608
  //   h        [4096]                  @ 8,454,144
  //   theta    [192]                   @ 8,458,240
  float* a1p     = ws;
  float* a2      = ws + (size_t)16777216;
  float* partial = ws;
  float* part2   = ws + (size_t)8388608;
  float* h       = ws + (size_t)8454144;
  float* th      = ws + (size_t)8458240;

  hipLaunchKernelGGL(conv1_k,       dim3(128, 32), dim3(256), 0, stream, in, k1, b1, a1p);
  hipLaunchKernelGGL(conv2_k,       dim3(32, 32),  dim3(256), 0, stream, a1p, k2, b2, a2);
  hipLaunchKernelGGL(fc1_partial_k, dim3(FC1_G),   dim3(256), 0, stream, a2, w1, partial);
  hipLaunchKernelGGL(fc1_reduce1_k, dim3(32, GC1), dim3(128), 0, stream, partial, part2);
  hipLaunchKernelGGL(fc1_reduce2_k, dim3(16),      dim3(256), 0, stream, part2, d1, h);
  hipLaunchKernelGGL(theta_k,       dim3(1),       dim3(192), 0, stream, h, w2, d2, th);
  hipLaunchKernelGGL(sample_k,      dim3(NB*IN_H), dim3(256), 0, stream, in, th, out);
}

// Round 6
// 348.836 us; speedup vs baseline: 1.1267x; 1.0341x over previous
//
#include <hip/hip_runtime.h>

#define IN_H 256
#define IN_W 256
#define C0   3
#define C1   32
#define H1   128
#define C2   64
#define H2   64
#define NB   32
#define K_FLAT (H2*H2*C2)   // 262144
#define NHID 128

// a1 layout: [b][parity 2][y 128][ci 32][x2 64], x = 2*x2 + parity.
#define A1_IDX(b,p,y,ci,x2) ((((((size_t)(b)*2 + (p))*H1 + (y))*C1 + (ci))*64) + (x2))

// ---------------------------------------------------------------- conv1
// in [32,256,256,3] -> a1p (planar layout above), stride2 SAME, ReLU.
__global__ __launch_bounds__(256, 8)
void conv1_k(const float* __restrict__ in, const float* __restrict__ k1,
             const float* __restrict__ b1, float* __restrict__ a1p) {
  const int tid = threadIdx.x;
  const int ox  = tid & 127;                                       // 0..127
  const int cg  = __builtin_amdgcn_readfirstlane((tid >> 7) * 16); // 0 or 16
  const int oy  = blockIdx.x;       // 0..127
  const int b   = blockIdx.y;       // 0..31

  float acc[16];
#pragma unroll
  for (int co = 0; co < 16; ++co) acc[co] = b1[cg + co];

#pragma unroll
  for (int dy = 0; dy < 3; ++dy) {
    const int iy  = 2*oy + dy;
    if (iy >= IN_H) continue;        // block-uniform for oy==127
#pragma unroll
    for (int dx = 0; dx < 3; ++dx) {
      const int ix  = 2*ox + dx;
      const bool ok = ix < IN_W;     // per-lane only for ox==127, dx==2
      const int ixc = ok ? ix : (IN_W-1);
      const float* ip = in + ((size_t)(b*IN_H + iy)*IN_W + ixc)*C0;
      const float m  = ok ? 1.f : 0.f;
      const float v0 = ip[0] * m;
      const float v1 = ip[1] * m;
      const float v2 = ip[2] * m;
      const float* wp = k1 + (size_t)((dy*3+dx)*C0)*C1 + cg;   // [ci][co]
#pragma unroll
      for (int co = 0; co < 16; ++co)
        acc[co] = fmaf(v0, wp[co],
                  fmaf(v1, wp[C1+co],
                  fmaf(v2, wp[2*C1+co], acc[co])));
    }
  }
  const int p  = ox & 1;
  const int x2 = ox >> 1;
#pragma unroll
  for (int co = 0; co < 16; ++co)
    a1p[A1_IDX(b, p, oy, cg + co, x2)] = fmaxf(acc[co], 0.f);
}

// ---------------------------------------------------------------- conv2
// a1p (planar) -> a2 [32,64,64,64] NHWC, stride2 SAME, ReLU.
// v4 = v2 structure + __launch_bounds__(256,4) + unroll 8 (R4: worked).
#define CONV2_DY_LOOP(EDGE_)                                                   \
  _Pragma("unroll")                                                            \
  for (int dy = 0; dy < 3; ++dy) {                                             \
    int iy = 2*oy + dy;                                                        \
    float rm = 1.f;                                                            \
    if (EDGE_) { if (iy >= H1) { iy = H1 - 1; rm = 0.f; } }                    \
    const float* r0 = a1p + A1_IDX(b, 0, iy, 0, 0) + 2*lx;                     \
    const float* r1 = a1p + A1_IDX(b, 1, iy, 0, 0) + 2*lx;                     \
    const float* wp = k2 + (size_t)(dy*3*C1)*C2 + cg16;                        \
    const float m2 = EDGE_ ? rm * xm : xm;                                     \
    _Pragma("unroll 8")                                                        \
    for (int ci = 0; ci < C1; ++ci) {                                          \
      const float2 Av = *(const float2*)(r0 + (size_t)ci*64);                  \
      const float  A2 = r0[(size_t)ci*64 + 2];                                 \
      const float2 Bv = *(const float2*)(r1 + (size_t)ci*64);                  \
      const float ax = EDGE_ ? Av.x*rm : Av.x;                                 \
      const float ay = EDGE_ ? Av.y*rm : Av.y;                                 \
      const float bx = EDGE_ ? Bv.x*rm : Bv.x;                                 \
      const float by = EDGE_ ? Bv.y*rm : Bv.y;                                 \
      const float a2v = A2 * m2;                                               \
      const float* w0  = wp + (size_t)ci*C2;                                   \
      const float* w1r = wp + (size_t)(C1 + ci)*C2;                            \
      const float* w2r = wp + (size_t)(2*C1 + ci)*C2;                          \
      _Pragma("unroll")                                                        \
      for (int co = 0; co < 16; ++co) {                                        \
        acc0[co] = fmaf(ax, w0[co],                                            \
                   fmaf(bx, w1r[co],                                           \
                   fmaf(ay,  w2r[co], acc0[co])));                             \
        acc1[co] = fmaf(ay, w0[co],                                            \
                   fmaf(by, w1r[co],                                           \
                   fmaf(a2v, w2r[co], acc1[co])));                             \
      }                                                                        \
    }                                                                          \
  }

__global__ __launch_bounds__(256, 4)
void conv2_k(const float* __restrict__ a1p, const float* __restrict__ k2,
             const float* __restrict__ b2, float* __restrict__ a2) {
  const int tid  = threadIdx.x;
  const int lane = tid & 63;
  const int lx   = lane & 31;                                       // ox pair
  const int oys  = lane >> 5;                                       // 0/1
  const int cg16 = __builtin_amdgcn_readfirstlane((tid >> 6) * 16); // co base
  const int oy   = blockIdx.x * 2 + oys;                            // 0..63
  const int b    = blockIdx.y;

  float acc0[16], acc1[16];
#pragma unroll
  for (int co = 0; co < 16; ++co) { acc0[co] = b2[cg16 + co]; acc1[co] = acc0[co]; }

  // ox1 = 2lx+1 == 63 has its dx=2 tap at x=128 (SAME pad) -> masked.
  const float xm = (lx == 31) ? 0.f : 1.f;

  if (blockIdx.x == 31) {            // contains oy=63: dy=2 row invalid (per-lane)
    CONV2_DY_LOOP(1)
  } else {
    CONV2_DY_LOOP(0)
  }

  float* op = a2 + ((size_t)((b*H2 + oy)*H2) + 2*lx)*C2 + cg16;
#pragma unroll
  for (int g = 0; g < 4; ++g) {
    float4 o0;
    o0.x = fmaxf(acc0[4*g+0], 0.f);
    o0.y = fmaxf(acc0[4*g+1], 0.f);
    o0.z = fmaxf(acc0[4*g+2], 0.f);
    o0.w = fmaxf(acc0[4*g+3], 0.f);
    ((float4*)op)[g] = o0;
    float4 o1;
    o1.x = fmaxf(acc1[4*g+0], 0.f);
    o1.y = fmaxf(acc1[4*g+1], 0.f);
    o1.z = fmaxf(acc1[4*g+2], 0.f);
    o1.w = fmaxf(acc1[4*g+3], 0.f);
    ((float4*)(op + C2))[g] = o1;
  }
}

// ---------------------------------------------------------------- FC1 partial
// x = a2 flat [32, 262144]; w1 [262144, 128].
// v4 (R5 post-mortem: launch_bounds hints did NOT unlock register
// pipelining of the streaming w-load; VALUBusy stuck ~20%). New structure:
// stage BOTH operands in LDS per 64-k sub-round. The w-stage is 8
// independent float4 loads/thread (MLP=8 by construction, bulk-coalesced);
// the k-loop is then pure LDS (ds_read_b128 w-slice, conflict-free +
// broadcast xb) + FMA with zero global-latency exposure. 3 blocks/CU
// (41.9 KB LDS); HBM absorbed by staging overlapped across blocks.
#define FC1_G   2048
#define KSPAN   (K_FLAT / FC1_G)   // 128
#define SUB     64                 // k sub-round
#define GC1     16                 // reduce1 column-groups

__global__ __launch_bounds__(256, 3)
void fc1_partial_k(const float* __restrict__ a2, const float* __restrict__ w1,
                   float* __restrict__ partial) {
  __shared__ __align__(16) float wL[SUB*NHID];   // 32,768 B
  __shared__ __align__(16) float xT[SUB*36];     //  9,216 B
  const int tid = threadIdx.x;
  const int q   = tid & 31;    // n-quad: n = 4q..4q+3
  const int bo  = tid >> 5;    // 0..7 : b = 4bo..4bo+3
  const int k0  = blockIdx.x * KSPAN;

  float4 a0 = make_float4(0.f,0.f,0.f,0.f), a1v = a0, a2v = a0, a3v = a0;

#pragma unroll
  for (int r = 0; r < KSPAN/SUB; ++r) {
    const int ks = k0 + r*SUB;
    if (r) __syncthreads();          // protect LDS reuse across rounds

    // stage w1 chunk [SUB][128] linearly: 2048 float4, 8 per thread
    {
      const float4* wsrc = (const float4*)(w1 + (size_t)ks*NHID);
#pragma unroll
      for (int j = 0; j < 8; ++j)
        ((float4*)wL)[tid + j*256] = wsrc[tid + j*256];
    }
    // stage x chunk transposed: xT[k][b]
    {
      const int lb  = tid >> 3;    // 0..31
      const int lkq = tid & 7;
#pragma unroll
      for (int j = 0; j < 2; ++j) {
        const int k4 = lkq*4 + j*32;
        float4 t = *(const float4*)(a2 + (size_t)lb*K_FLAT + ks + k4);
        xT[(k4+0)*36 + lb] = t.x;
        xT[(k4+1)*36 + lb] = t.y;
        xT[(k4+2)*36 + lb] = t.z;
        xT[(k4+3)*36 + lb] = t.w;
      }
    }
    __syncthreads();

#pragma unroll 8
    for (int k = 0; k < SUB; ++k) {
      const float4 w4 = *(const float4*)(wL + k*NHID + 4*q);
      const float4 xb = *(const float4*)&xT[k*36 + 4*bo];
      a0.x = fmaf(xb.x, w4.x, a0.x); a0.y = fmaf(xb.x, w4.y, a0.y);
      a0.z = fmaf(xb.x, w4.z, a0.z); a0.w = fmaf(xb.x, w4.w, a0.w);
      a1v.x = fmaf(xb.y, w4.x, a1v.x); a1v.y = fmaf(xb.y, w4.y, a1v.y);
      a1v.z = fmaf(xb.y, w4.z, a1v.z); a1v.w = fmaf(xb.y, w4.w, a1v.w);
      a2v.x = fmaf(xb.z, w4.x, a2v.x); a2v.y = fmaf(xb.z, w4.y, a2v.y);
      a2v.z = fmaf(xb.z, w4.z, a2v.z); a2v.w = fmaf(xb.z, w4.w, a2v.w);
      a3v.x = fmaf(xb.w, w4.x, a3v.x); a3v.y = fmaf(xb.w, w4.y, a3v.y);
      a3v.z = fmaf(xb.w, w4.z, a3v.z); a3v.w = fmaf(xb.w, w4.w, a3v.w);
    }
  }

  float* pp = partial + (size_t)blockIdx.x*(NB*NHID) + 4*q;
  *(float4*)(pp + (4*bo+0)*NHID) = a0;
  *(float4*)(pp + (4*bo+1)*NHID) = a1v;
  *(float4*)(pp + (4*bo+2)*NHID) = a2v;
  *(float4*)(pp + (4*bo+3)*NHID) = a3v;
}

// ---------------------------------------------------------------- FC1 reduce stage 1: 2048 -> 16
__global__ __launch_bounds__(128, 8)
void fc1_reduce1_k(const float* __restrict__ partial, float* __restrict__ partial2) {
  const int t  = blockIdx.x*128 + threadIdx.x;  // 0..4095
  const int gc = blockIdx.y;                    // 0..15
  float s = 0.f;
#pragma unroll 8
  for (int g = gc*(FC1_G/GC1); g < gc*(FC1_G/GC1) + (FC1_G/GC1); ++g)
    s += partial[(size_t)g*(NB*NHID) + t];
  partial2[(size_t)gc*(NB*NHID) + t] = s;
}

// ---------------------------------------------------------------- FC1 reduce stage 2 (+bias+ReLU)
__global__ __launch_bounds__(256)
void fc1_reduce2_k(const float* __restrict__ partial2, const float* __restrict__ d1,
                   float* __restrict__ h) {
  const int t = blockIdx.x*256 + threadIdx.x;  // 0..4095
  float s = 0.f;
#pragma unroll
  for (int gc = 0; gc < GC1; ++gc) s += partial2[(size_t)gc*(NB*NHID) + t];
  h[t] = fmaxf(s + d1[t & (NHID-1)], 0.f);
}

// ---------------------------------------------------------------- theta = h @ w2 + d2
__global__ __launch_bounds__(192)
void theta_k(const float* __restrict__ h, const float* __restrict__ w2,
             const float* __restrict__ d2, float* __restrict__ theta) {
  const int t = threadIdx.x;
  if (t >= NB*6) return;
  const int b = t / 6, j = t % 6;
  float s0 = 0.f, s1 = 0.f, s2 = 0.f, s3 = 0.f;
  for (int n = 0; n < NHID; n += 4) {
    s0 = fmaf(h[b*NHID + n+0], w2[(n+0)*6 + j], s0);
    s1 = fmaf(h[b*NHID + n+1], w2[(n+1)*6 + j], s1);
    s2 = fmaf(h[b*NHID + n+2], w2[(n+2)*6 + j], s2);
    s3 = fmaf(h[b*NHID + n+3], w2[(n+3)*6 + j], s3);
  }
  theta[t] = (s0 + s1) + (s2 + s3) + d2[j];
}

// ---------------------------------------------------------------- grid sample (bilinear, zero pad)
__global__ __launch_bounds__(256)
void sample_k(const float* __restrict__ img, const float* __restrict__ theta,
              float* __restrict__ out) {
  const int x = threadIdx.x;
  const int y = blockIdx.x & (IN_H-1);
  const int b = blockIdx.x >> 8;
  const float* tp = theta + b*6;
  const float t0 = tp[0], t1 = tp[1], t2 = tp[2];
  const float t3 = tp[3], t4 = tp[4], t5 = tp[5];

  const float xs = (2.f*x + 1.f)*(1.f/IN_W) - 1.f;
  const float ys = (2.f*y + 1.f)*(1.f/IN_H) - 1.f;
  const float gx = fmaf(t0, xs, fmaf(t1, ys, t2));
  const float gy = fmaf(t3, xs, fmaf(t4, ys, t5));
  const float px = fmaf(gx + 1.f, 0.5f*IN_W, -0.5f);
  const float py = fmaf(gy + 1.f, 0.5f*IN_H, -0.5f);

  const float x0f = floorf(px), y0f = floorf(py);
  const int ix0 = (int)x0f, iy0 = (int)y0f;
  const float wx1 = px - x0f, wx0 = 1.f - wx1;
  const float wy1 = py - y0f, wy0 = 1.f - wy1;

  float r = 0.f, g = 0.f, bl = 0.f;
  const float* ib = img + (size_t)b*IN_H*IN_W*C0;

  auto tap = [&](int yi, int xi, float w) {
    const bool v = (xi >= 0) && (xi < IN_W) && (yi >= 0) && (yi < IN_H);
    const int xc = xi < 0 ? 0 : (xi > IN_W-1 ? IN_W-1 : xi);
    const int yc = yi < 0 ? 0 : (yi > IN_H-1 ? IN_H-1 : yi);
    const float* p = ib + ((size_t)yc*IN_W + xc)*C0;
    if (v) {
      r  = fmaf(w, p[0], r);
      g  = fmaf(w, p[1], g);
      bl = fmaf(w, p[2], bl);
    }
  };
  tap(iy0,   ix0,   wy0*wx0);
  tap(iy0,   ix0+1, wy0*wx1);
  tap(iy0+1, ix0,   wy1*wx0);
  tap(iy0+1, ix0+1, wy1*wx1);

  float* op = out + ((size_t)(b*IN_H + y)*IN_W + x)*C0;
  op[0] = r; op[1] = g; op[2] = bl;
}

// ---------------------------------------------------------------- launch
extern "C" void kernel_launch(void* const* d_in, const int* in_sizes, int n_in,
                              void* d_out, int out_size, void* d_ws, size_t ws_size,
                              hipStream_t stream) {
  const float* in = (const float*)d_in[0];
  const float* k1 = (const float*)d_in[1];
  const float* b1 = (const float*)d_in[2];
  const float* k2 = (const float*)d_in[3];
  const float* b2 = (const float*)d_in[4];
  const float* w1 = (const float*)d_in[5];
  const float* d1 = (const float*)d_in[6];
  const float* w2 = (const float*)d_in[7];
  const float* d2 = (const float*)d_in[8];
  float* out = (float*)d_out;
  float* ws  = (float*)d_ws;

  // ws layout (float offsets):
  //   a1p      [16,777,216] @ 0               (planar, exactly 64 MB)
  //   a2       [ 8,388,608] @ 16,777,216      (NHWC, matches flatten order)
  //   -- after conv2, a1p region is dead and reused: --
  //   partial  [2048*4096 = 8,388,608] @ 0
  //   partial2 [16*4096   =    65,536] @ 8,388,608
  //   h        [4096]                  @ 8,454,144
  //   theta    [192]                   @ 8,458,240
  float* a1p     = ws;
  float* a2      = ws + (size_t)16777216;
  float* partial = ws;
  float* part2   = ws + (size_t)8388608;
  float* h       = ws + (size_t)8454144;
  float* th      = ws + (size_t)8458240;

  hipLaunchKernelGGL(conv1_k,       dim3(128, 32), dim3(256), 0, stream, in, k1, b1, a1p);
  hipLaunchKernelGGL(conv2_k,       dim3(32, 32),  dim3(256), 0, stream, a1p, k2, b2, a2);
  hipLaunchKernelGGL(fc1_partial_k, dim3(FC1_G),   dim3(256), 0, stream, a2, w1, partial);
  hipLaunchKernelGGL(fc1_reduce1_k, dim3(32, GC1), dim3(128), 0, stream, partial, part2);
  hipLaunchKernelGGL(fc1_reduce2_k, dim3(16),      dim3(256), 0, stream, part2, d1, h);
  hipLaunchKernelGGL(theta_k,       dim3(1),       dim3(192), 0, stream, h, w2, d2, th);
  hipLaunchKernelGGL(sample_k,      dim3(NB*IN_H), dim3(256), 0, stream, in, th, out);
}